// Round 10
// baseline (152.312 us; speedup 1.0000x reference)
//
#include <hip/hip_runtime.h>
#include <stdint.h>

#define M_DIM 8192   // K of the Gram GEMM
#define N_DIM 4096   // output N x N

typedef __attribute__((ext_vector_type(4))) int i32x4;
typedef __attribute__((ext_vector_type(8))) int i32x8;
typedef __attribute__((ext_vector_type(16))) float f32x16;

// fp32 -> OCP e4m3 (RNE, FTZ below 2^-6, saturate to 448)
__device__ __forceinline__ unsigned char f2e4m3(float x) {
  union { float f; uint32_t u; } v;
  v.f = x;
  const uint32_t s = (v.u >> 24) & 0x80;
  const uint32_t au = v.u & 0x7fffffffu;
  if (au < 0x3c800000u) return (unsigned char)s;  // |x| < 2^-6 -> 0
  const uint32_t r = au + 0x7ffffu + ((au >> 20) & 1u);  // RNE at 3 mantissa bits
  int e = (int)(r >> 23) - 127;
  uint32_t m = (r >> 20) & 7u;
  if (e > 8 || (e == 8 && m == 7)) { e = 8; m = 6; }  // sat 448, avoid NaN
  return (unsigned char)(s | ((uint32_t)(e + 7) << 3) | m);
}

__device__ __forceinline__ void gl_lds16b(const char* g, char* l) {
  __builtin_amdgcn_global_load_lds(
      (const __attribute__((address_space(1))) void*)g,
      (__attribute__((address_space(3))) void*)l, 16, 0, 0);
}

#define CFENCE asm volatile("" ::: "memory")

// ---------------- Kernel 1: A[M][N] fp32 -> At[N][M] fp8, plain linear rows.
__global__ __launch_bounds__(256) void transpose_convert_fp8(
    const float* __restrict__ A, unsigned char* __restrict__ At) {
  __shared__ unsigned char tile[64][68];
  const int bm = blockIdx.x % (M_DIM / 64);
  const int bn = blockIdx.x / (M_DIM / 64);
  const int m0 = bm * 64, n0 = bn * 64;
  const int t = threadIdx.x;
  const int tr = t >> 4;
  const int tc = (t & 15) << 2;
#pragma unroll
  for (int p = 0; p < 4; ++p) {
    const int r = p * 16 + tr;
    const float4 v = *reinterpret_cast<const float4*>(
        &A[(size_t)(m0 + r) * N_DIM + (n0 + tc)]);
    tile[tc + 0][r] = f2e4m3(v.x);
    tile[tc + 1][r] = f2e4m3(v.y);
    tile[tc + 2][r] = f2e4m3(v.z);
    tile[tc + 3][r] = f2e4m3(v.w);
  }
  __syncthreads();
#pragma unroll
  for (int p = 0; p < 4; ++p) {
    const int rn = p * 16 + tr;
    uchar4 o;
    o.x = tile[rn][tc + 0];
    o.y = tile[rn][tc + 1];
    o.z = tile[rn][tc + 2];
    o.w = tile[rn][tc + 3];
    *reinterpret_cast<uchar4*>(
        &At[(size_t)(n0 + rn) * M_DIM + (m0 + tc)]) = o;
  }
}

// ---------------- Kernel 2: 256x256 tile, 4 waves in 2x2 grid (128x128 each)
// -> LDS read amplification A2x/B2x = 64KB/iter (was 96). MX-scaled
// mfma_scale_f32_32x32x64_f8f6f4, unit scales. 4 LDS bufs of 32KB,
// stage S+3, counted vmcnt(16), one barrier/iter, R8-verified order
// {reads -> STG -> MFMA}. Swizzle (involution): byte d -> d ^ ((d>>7)&3)<<4.
__global__ __launch_bounds__(256, 1) void gram_fp8s(
    const unsigned char* __restrict__ At, float* __restrict__ C) {
  __shared__ char smem[131072];

  const int bid = (int)blockIdx.x;
  const int wg = (bid & 7) * 32 + (bid >> 3);  // XCD swizzle (256 % 8 == 0)
  const int bi = wg >> 4, bj = wg & 15;

  const int t = (int)threadIdx.x;
  const int lane = t & 63, wave = t >> 6;
  const int wr = wave >> 1, wc = wave & 1;   // 2x2 grid: 128x128 per wave
  const int l31 = lane & 31, hi = lane >> 5;

  // fragment read addresses (two b128 per 32x32 operand block)
  const int sw = ((l31 >> 1) & 3) << 4;
  const int c0 = (hi * 32) ^ sw;
  const int c1 = (hi * 32 + 16) ^ sw;
  int adA0[4], adA1[4], adB0[4], adB1[4];
#pragma unroll
  for (int mb = 0; mb < 4; ++mb) {
    const int row = wr * 128 + mb * 32 + l31;
    adA0[mb] = row * 64 + c0;
    adA1[mb] = row * 64 + c1;
  }
#pragma unroll
  for (int nb = 0; nb < 4; ++nb) {
    const int row = wc * 128 + nb * 32 + l31;
    adB0[nb] = 16384 + row * 64 + c0;
    adB1[nb] = 16384 + row * 64 + c1;
  }

  // staging: 256 threads x 16B = 4KB/instr; 4 row-groups of 64 per region.
  // LDS row (local) = g*64 + (t>>2); source col = ((t&3)^((t>>3)&3))*16
  // (same swizzle algebra verified 0-conflict in R5/R8).
  const char* const Atb = (const char*)At;
  const size_t MB = (size_t)M_DIM;   // bytes per At row (fp8)
  const int rq = t >> 2;             // 0..63
  const int cs = ((t & 3) ^ ((t >> 3) & 3)) * 16;
  const char* const sA = Atb + (size_t)(bi * 256 + rq) * MB + cs;
  const char* const sB = Atb + (size_t)(bj * 256 + rq) * MB + cs;
  const int dd = t * 16;             // dest within 4KB group

  f32x16 acc[4][4] = {};

  // prologue: stage K-chunks 0,1,2 into bufs 0,1,2 (8 gl_lds each)
#pragma unroll
  for (int ss = 0; ss < 3; ++ss) {
    char* const b = smem + ss * 32768;
    const size_t ko = (size_t)ss * 64;
#pragma unroll
    for (int g = 0; g < 4; ++g) {
      gl_lds16b(sA + (size_t)g * 64 * MB + ko, b + g * 4096 + dd);
      gl_lds16b(sB + (size_t)g * 64 * MB + ko, b + 16384 + g * 4096 + dd);
    }
  }

#define ITER(S, STG, VMW) do {                                               \
  if ((VMW) == 16)     asm volatile("s_waitcnt vmcnt(16)" ::: "memory");     \
  else if ((VMW) == 8) asm volatile("s_waitcnt vmcnt(8)" ::: "memory");      \
  else if ((VMW) == 0) asm volatile("s_waitcnt vmcnt(0)" ::: "memory");      \
  __builtin_amdgcn_s_barrier();                                              \
  CFENCE;                                                                    \
  {                                                                          \
    const char* const bb = smem + ((S) & 3) * 32768;                         \
    i32x8 av[4], bv[4];                                                      \
    _Pragma("unroll") for (int mb = 0; mb < 4; ++mb) {                       \
      const i32x4 lo = *reinterpret_cast<const i32x4*>(bb + adA0[mb]);       \
      const i32x4 hi_ = *reinterpret_cast<const i32x4*>(bb + adA1[mb]);      \
      av[mb] = __builtin_shufflevector(lo, hi_, 0, 1, 2, 3, 4, 5, 6, 7);     \
    }                                                                        \
    _Pragma("unroll") for (int nb = 0; nb < 4; ++nb) {                       \
      const i32x4 lo = *reinterpret_cast<const i32x4*>(bb + adB0[nb]);       \
      const i32x4 hi_ = *reinterpret_cast<const i32x4*>(bb + adB1[nb]);      \
      bv[nb] = __builtin_shufflevector(lo, hi_, 0, 1, 2, 3, 4, 5, 6, 7);     \
    }                                                                        \
    if (STG) {                                                               \
      char* const sbf = smem + (((S) + 3) & 3) * 32768;                      \
      const size_t ko = (size_t)((S) + 3) * 64;                              \
      _Pragma("unroll") for (int g = 0; g < 4; ++g) {                        \
        gl_lds16b(sA + (size_t)g * 64 * MB + ko, sbf + g * 4096 + dd);       \
        gl_lds16b(sB + (size_t)g * 64 * MB + ko, sbf + 16384 + g * 4096 + dd); \
      }                                                                      \
    }                                                                        \
    _Pragma("unroll") for (int mb = 0; mb < 4; ++mb)                         \
      _Pragma("unroll") for (int nb = 0; nb < 4; ++nb)                       \
        acc[mb][nb] = __builtin_amdgcn_mfma_scale_f32_32x32x64_f8f6f4(       \
            av[mb], bv[nb], acc[mb][nb], 0, 0,                               \
            0, 0x7F7F7F7F, 0, 0x7F7F7F7F);                                   \
  }                                                                          \
} while (0)

  // 128 K-chunks of 64; stage chunk S+3 in iters 0..124
  for (int s = 0; s < 124; s += 4) {
    ITER(s + 0, true, 16);
    ITER(s + 1, true, 16);
    ITER(s + 2, true, 16);
    ITER(s + 3, true, 16);
  }
  ITER(124, true, 16);   // stages chunk 127
  ITER(125, false, 16);
  ITER(126, false, 8);
  ITER(127, false, 0);

#undef ITER

  // epilogue: 32x32 C/D map (verified R6/R9): col = lane&31,
  // row = (reg&3) + 8*(reg>>2) + 4*(lane>>5)
  const int rb = bi * 256 + wr * 128;
  const int cb = bj * 256 + wc * 128;
#pragma unroll
  for (int mb = 0; mb < 4; ++mb) {
#pragma unroll
    for (int nb = 0; nb < 4; ++nb) {
      const int c = cb + nb * 32 + l31;
#pragma unroll
      for (int rg = 0; rg < 4; ++rg) {
        const int r0 = rb + mb * 32 + rg * 8 + hi * 4;
#pragma unroll
        for (int j = 0; j < 4; ++j)
          C[(size_t)(r0 + j) * N_DIM + c] = acc[mb][nb][rg * 4 + j];
      }
    }
  }
}

extern "C" void kernel_launch(void* const* d_in, const int* in_sizes, int n_in,
                              void* d_out, int out_size, void* d_ws, size_t ws_size,
                              hipStream_t stream) {
  const float* A = (const float*)d_in[0];
  float* C = (float*)d_out;
  unsigned char* At = (unsigned char*)d_ws;  // 4096*8192 = 32 MiB

  transpose_convert_fp8<<<dim3((M_DIM / 64) * (N_DIM / 64)), 256, 0, stream>>>(A, At);
  gram_fp8s<<<dim3(16 * 16), 256, 0, stream>>>(At, C);
}

// Round 11
// 138.323 us; speedup vs baseline: 1.1011x; 1.1011x over previous
//
#include <hip/hip_runtime.h>
#include <stdint.h>

#define M_DIM 8192   // K of the Gram GEMM
#define N_DIM 4096   // output N x N

typedef __attribute__((ext_vector_type(4))) int i32x4;
typedef __attribute__((ext_vector_type(8))) int i32x8;
typedef __attribute__((ext_vector_type(16))) float f32x16;

// fp32 -> OCP e4m3 (RNE, FTZ below 2^-6, saturate to 448)
__device__ __forceinline__ unsigned char f2e4m3(float x) {
  union { float f; uint32_t u; } v;
  v.f = x;
  const uint32_t s = (v.u >> 24) & 0x80;
  const uint32_t au = v.u & 0x7fffffffu;
  if (au < 0x3c800000u) return (unsigned char)s;  // |x| < 2^-6 -> 0
  const uint32_t r = au + 0x7ffffu + ((au >> 20) & 1u);  // RNE at 3 mantissa bits
  int e = (int)(r >> 23) - 127;
  uint32_t m = (r >> 20) & 7u;
  if (e > 8 || (e == 8 && m == 7)) { e = 8; m = 6; }  // sat 448, avoid NaN
  return (unsigned char)(s | ((uint32_t)(e + 7) << 3) | m);
}

__device__ __forceinline__ void gl_lds16b(const char* g, char* l) {
  __builtin_amdgcn_global_load_lds(
      (const __attribute__((address_space(1))) void*)g,
      (__attribute__((address_space(3))) void*)l, 16, 0, 0);
}

#define CFENCE asm volatile("" ::: "memory")

// ---------------- Kernel 1: A[M][N] fp32 -> At packed operand-major fp8.
// At layout: [nblk(16)][kc(128)][g(8)][c(4)][r32(32)][byte e(16)]
//   element (n, k): nblk=n>>8, kc=k>>6, g=(n>>5)&7, c=(k>>4)&3, r32=n&31, e=k&15
// 16KB block per (nblk,kc); GEMM stages it as a plain linear copy and reads
// operands as two contiguous 512B regions per wave (0-conflict class).
__global__ __launch_bounds__(256) void transpose_pack_fp8(
    const float* __restrict__ A, unsigned char* __restrict__ At) {
  __shared__ unsigned char tile[64][68];  // tile[x][y] = A[m0+y][n0+x]
  const int bm = blockIdx.x % (M_DIM / 64);
  const int bn = blockIdx.x / (M_DIM / 64);
  const int m0 = bm * 64, n0 = bn * 64;
  const int t = threadIdx.x;
  const int tr = t >> 4;
  const int tc = (t & 15) << 2;
#pragma unroll
  for (int p = 0; p < 4; ++p) {
    const int r = p * 16 + tr;  // m_local
    const float4 v = *reinterpret_cast<const float4*>(
        &A[(size_t)(m0 + r) * N_DIM + (n0 + tc)]);
    tile[tc + 0][r] = f2e4m3(v.x);
    tile[tc + 1][r] = f2e4m3(v.y);
    tile[tc + 2][r] = f2e4m3(v.z);
    tile[tc + 3][r] = f2e4m3(v.w);
  }
  __syncthreads();
  const int cC = (tc >> 4) & 3;   // k-chunk within 64
  const int eC = tc & 15;         // byte within 16B chunk
  const int nblk = n0 >> 8;
  const int kc = m0 >> 6;
  unsigned char* const obase = At + ((size_t)(nblk * 128 + kc) * 8) * 2048;
#pragma unroll
  for (int p = 0; p < 4; ++p) {
    const int rn = p * 16 + tr;       // n_local
    const int n = n0 + rn;
    const int g = (n >> 5) & 7;
    const int r32 = n & 31;
    uchar4 o;
    o.x = tile[rn][tc + 0];  // k = m0+tc+0 .. +3
    o.y = tile[rn][tc + 1];
    o.z = tile[rn][tc + 2];
    o.w = tile[rn][tc + 3];
    *reinterpret_cast<uchar4*>(
        &obase[g * 2048 + cC * 512 + r32 * 16 + eC]) = o;
  }
}

// ---------------- Kernel 2: 256x256 tile, 8 waves (2x4, wave 128x64),
// MX-scaled mfma_scale_f32_32x32x64_f8f6f4 (unit scales 0x7F = 2^0, exact).
// 4 LDS bufs of 32KB (A-chunk 16KB @0, B-chunk @16384), stage S+3,
// vmcnt(8), one barrier/iter, order {reads -> STG -> MFMA} (R8-verified).
__global__ __launch_bounds__(512, 1) void gram_fp8s(
    const unsigned char* __restrict__ At, float* __restrict__ C) {
  __shared__ char smem[131072];

  const int bid = (int)blockIdx.x;
  const int wg = (bid & 7) * 32 + (bid >> 3);  // XCD swizzle (256 % 8 == 0)
  const int bi = wg >> 4, bj = wg & 15;

  const int t = (int)threadIdx.x;
  const int lane = t & 63, wave = t >> 6;
  const int wr = wave >> 2, wc = wave & 3;   // wave tile: rows wr*128, cols wc*64
  const int l31 = lane & 31, hi = lane >> 5;

  // operand read addresses: group block @ g*2048; chunks c = 2hi, 2hi+1
  int adA0[4], adB0[2];
#pragma unroll
  for (int mb = 0; mb < 4; ++mb)
    adA0[mb] = (wr * 4 + mb) * 2048 + hi * 1024 + l31 * 16;
#pragma unroll
  for (int nb = 0; nb < 2; ++nb)
    adB0[nb] = 16384 + (wc * 2 + nb) * 2048 + hi * 1024 + l31 * 16;

  // staging: plain linear 16KB copies (packed global layout == LDS layout)
  const char* const Atb = (const char*)At;
  const char* const sAc = Atb + (size_t)bi * (128 * 16384);
  const char* const sBc = Atb + (size_t)bj * (128 * 16384);
  const int dd = t * 16;  // 0..8176

  f32x16 acc[4][2] = {};

  // prologue: stage K-chunks 0,1,2 into bufs 0,1,2 (4 gl_lds each)
#pragma unroll
  for (int ss = 0; ss < 3; ++ss) {
    char* const b = smem + ss * 32768;
    const size_t ko = (size_t)ss * 16384;
    gl_lds16b(sAc + ko + dd, b + dd);
    gl_lds16b(sAc + ko + 8192 + dd, b + 8192 + dd);
    gl_lds16b(sBc + ko + dd, b + 16384 + dd);
    gl_lds16b(sBc + ko + 8192 + dd, b + 16384 + 8192 + dd);
  }

#define ITER(S, STG, VMW) do {                                               \
  if ((VMW) == 8)      asm volatile("s_waitcnt vmcnt(8)" ::: "memory");      \
  else if ((VMW) == 4) asm volatile("s_waitcnt vmcnt(4)" ::: "memory");      \
  else if ((VMW) == 0) asm volatile("s_waitcnt vmcnt(0)" ::: "memory");      \
  __builtin_amdgcn_s_barrier();                                              \
  CFENCE;                                                                    \
  {                                                                          \
    const char* const bb = smem + ((S) & 3) * 32768;                         \
    i32x8 av[4], bv[2];                                                      \
    _Pragma("unroll") for (int mb = 0; mb < 4; ++mb) {                       \
      const i32x4 lo = *reinterpret_cast<const i32x4*>(bb + adA0[mb]);       \
      const i32x4 hv = *reinterpret_cast<const i32x4*>(bb + adA0[mb] + 512); \
      av[mb] = __builtin_shufflevector(lo, hv, 0, 1, 2, 3, 4, 5, 6, 7);      \
    }                                                                        \
    _Pragma("unroll") for (int nb = 0; nb < 2; ++nb) {                       \
      const i32x4 lo = *reinterpret_cast<const i32x4*>(bb + adB0[nb]);       \
      const i32x4 hv = *reinterpret_cast<const i32x4*>(bb + adB0[nb] + 512); \
      bv[nb] = __builtin_shufflevector(lo, hv, 0, 1, 2, 3, 4, 5, 6, 7);      \
    }                                                                        \
    if (STG) {                                                               \
      char* const sbf = smem + (((S) + 3) & 3) * 32768;                      \
      const size_t ko = (size_t)((S) + 3) * 16384;                           \
      gl_lds16b(sAc + ko + dd, sbf + dd);                                    \
      gl_lds16b(sAc + ko + 8192 + dd, sbf + 8192 + dd);                      \
      gl_lds16b(sBc + ko + dd, sbf + 16384 + dd);                            \
      gl_lds16b(sBc + ko + 8192 + dd, sbf + 16384 + 8192 + dd);              \
    }                                                                        \
    _Pragma("unroll") for (int mb = 0; mb < 4; ++mb)                         \
      _Pragma("unroll") for (int nb = 0; nb < 2; ++nb)                       \
        acc[mb][nb] = __builtin_amdgcn_mfma_scale_f32_32x32x64_f8f6f4(       \
            av[mb], bv[nb], acc[mb][nb], 0, 0,                               \
            0, 0x7F7F7F7F, 0, 0x7F7F7F7F);                                   \
  }                                                                          \
} while (0)

  // 128 K-chunks of 64; stage chunk S+3 in iters 0..124
  for (int s = 0; s < 124; s += 4) {
    ITER(s + 0, true, 8);
    ITER(s + 1, true, 8);
    ITER(s + 2, true, 8);
    ITER(s + 3, true, 8);
  }
  ITER(124, true, 8);    // stages chunk 127
  ITER(125, false, 8);
  ITER(126, false, 4);
  ITER(127, false, 0);

#undef ITER

  // epilogue: 32x32 C/D map (verified R6/R9): col = lane&31,
  // row = (reg&3) + 8*(reg>>2) + 4*(lane>>5)
  const int rb = bi * 256 + wr * 128;
  const int cb = bj * 256 + wc * 64;
#pragma unroll
  for (int mb = 0; mb < 4; ++mb) {
#pragma unroll
    for (int nb = 0; nb < 2; ++nb) {
      const int c = cb + nb * 32 + l31;
#pragma unroll
      for (int rg = 0; rg < 4; ++rg) {
        const int r0 = rb + mb * 32 + rg * 8 + hi * 4;
#pragma unroll
        for (int j = 0; j < 4; ++j)
          C[(size_t)(r0 + j) * N_DIM + c] = acc[mb][nb][rg * 4 + j];
      }
    }
  }
}

extern "C" void kernel_launch(void* const* d_in, const int* in_sizes, int n_in,
                              void* d_out, int out_size, void* d_ws, size_t ws_size,
                              hipStream_t stream) {
  const float* A = (const float*)d_in[0];
  float* C = (float*)d_out;
  unsigned char* At = (unsigned char*)d_ws;  // 32 MiB packed

  transpose_pack_fp8<<<dim3((M_DIM / 64) * (N_DIM / 64)), 256, 0, stream>>>(A, At);
  gram_fp8s<<<dim3(16 * 16), 512, 0, stream>>>(At, C);
}